// Round 6
// baseline (443.632 us; speedup 1.0000x reference)
//
#include <hip/hip_runtime.h>
#include <hip/hip_bf16.h>
#include <math.h>

// ---------------------------------------------------------------------------
// SimpleMoEModel: dense GEMM -> top1-MoE -> top1-MoE -> residual -> mean ->
// log_softmax -> NLL.  B=8 S=2048 D=1024 E=8, capacity = T/E = 2048.
//
// Round 17: r16 (376.4 us). rocprof r16: GEMMs 49.7 us ea (MfmaUtil 25%,
// 691 TF) -- the 4-phase/8-barrier schedule stalls on collective barriers +
// lgkmcnt(0) full drains at 2 waves/SIMD. reduce 50 us (occupancy 7.7%,
// latency-bound at 8 waves/CU).
// Fixes:
//  GEMM -> 128x256/BK=64 TRIPLE-buffered LDS (3x48 KB = 144 KB), ONE
//   barrier per K-tile: stage tile t+2 -> buf (t+2)%3 (last read tile t-1,
//   reads completed before t-1-close barrier since every ds_read feeds an
//   MFMA before it; sched_barrier(0) pins the cluster, rule #18). Loop =
//   {stage 6 gll, 16 ds_read + 32 MFMA compiler-interleaved, vmcnt(6),
//   barrier}. No manual lgkmcnt; counted vmcnt never 0 in steady state.
//   Grid 512 blocks (2 rounds/CU). Wave = 64x64 out, acc[4][4].
//  reduce L1 512 -> 1024 blocks (16 rows ea, 8-deep uint4) -> 4 MB partials;
//   L2 per-batch tails read 128 L2-hot rows; 3-level fence tree unchanged.
// prep_w/prep_x/gate/route byte-identical to r16.
// ---------------------------------------------------------------------------

#define TOKS 16384
#define DIM 1024
#define NEXP 8
#define CAP 2048
#define BATCH 8
#define SEQ 2048

typedef __bf16 bf16_t;
typedef __bf16 bf16x8 __attribute__((ext_vector_type(8)));
typedef float fx4 __attribute__((ext_vector_type(4)));

__device__ __forceinline__ void gll16(const bf16_t* g, bf16_t* l) {
  __builtin_amdgcn_global_load_lds(
      (const __attribute__((address_space(1))) unsigned int*)g,
      (__attribute__((address_space(3))) unsigned int*)l, 16, 0, 0);
}

#define BARRIER() asm volatile("s_barrier" ::: "memory")
#define VMC(N)    asm volatile("s_waitcnt vmcnt(" #N ")" ::: "memory")

// ---------------- prep A: weight transpose+cvt (17 x 1024^2) ---------------
#define PW_BLOCKS (17 * 64)
__global__ __launch_bounds__(256) void k_prep_w(
    const float* __restrict__ W1, const float* __restrict__ We2,
    const float* __restrict__ We3, bf16_t* __restrict__ Wt) {
  __shared__ bf16_t T[256][68];  // 34.8 KB; row stride 136 B (b64-aligned)
  const int id = blockIdx.x;
  const int tid = threadIdx.x;
  const int m = id >> 6, rem = id & 63;
  const int k0 = (rem >> 4) * 256, n0 = (rem & 15) * 64;
  const float* src = (m == 0) ? W1
                     : (m <= 8) ? We2 + (size_t)(m - 1) * DIM * DIM
                                : We3 + (size_t)(m - 9) * DIM * DIM;
  bf16_t* dst = Wt + (size_t)m * DIM * DIM;
  const int r = tid >> 4, nq = tid & 15;
#pragma unroll
  for (int i = 0; i < 16; i++) {
    const int k = i * 16 + r;
    float4 v = *(const float4*)&src[(size_t)(k0 + k) * DIM + n0 + nq * 4];
    union { bf16_t h[4]; uint2 u; } t;
    t.h[0] = (bf16_t)v.x; t.h[1] = (bf16_t)v.y;
    t.h[2] = (bf16_t)v.z; t.h[3] = (bf16_t)v.w;
    *(uint2*)&T[k][(nq ^ ((k >> 3) & 15)) << 2] = t.u;  // XOR col swizzle
  }
  __syncthreads();
#pragma unroll
  for (int p = 0; p < 8; p++) {
    const int idx2 = p * 256 + tid;
    const int nl = idx2 >> 5, ks = (idx2 & 31) * 8;
    union { bf16_t h[8]; uint4 u; } o;
#pragma unroll
    for (int j = 0; j < 8; j++) {
      const int k = ks + j;
      o.h[j] = T[k][((((nl >> 2) ^ ((k >> 3) & 15)) << 2) | (nl & 3))];
    }
    *(uint4*)&dst[(size_t)(n0 + nl) * DIM + k0 + ks] = o.u;
  }
}

// ---------------- prep B: Wg pack | x cvt | zero-fill ----------------------
#define CVT_BLOCKS (TOKS * DIM / 8 / 256)
#define PREPX_GRID (2 + CVT_BLOCKS + 1)
__global__ __launch_bounds__(256) void k_prep_x(
    const float* __restrict__ Wg2, const float* __restrict__ Wg3,
    const float* __restrict__ x, bf16_t* __restrict__ WgP,
    bf16_t* __restrict__ xb, uint4* __restrict__ zreg, int znq) {
  const int id = blockIdx.x;
  const int tid = threadIdx.x;
  if (id < 2) {
    const int which = id;
    const float* src = which ? Wg3 : Wg2;
    bf16_t* dst = WgP + which * (128 * 8 * 8);
#pragma unroll
    for (int j = 0; j < 4; j++) {
      int d = tid * 4 + j;
      float4 a = *(const float4*)&src[d * 8];
      float4 b = *(const float4*)&src[d * 8 + 4];
      float v[8] = {a.x, a.y, a.z, a.w, b.x, b.y, b.z, b.w};
#pragma unroll
      for (int e = 0; e < 8; e++)
        dst[((d >> 3) * 8 + e) * 8 + (d & 7)] = (bf16_t)v[e];
    }
  } else if (id < 2 + CVT_BLOCKS) {
    const int cid = id - 2;
    size_t i = ((size_t)cid * 256 + tid) * 8;
    float4 a = *(const float4*)&x[i];
    float4 b = *(const float4*)&x[i + 4];
    union { bf16_t h[8]; uint4 u; } t;
    t.h[0] = (bf16_t)a.x; t.h[1] = (bf16_t)a.y; t.h[2] = (bf16_t)a.z; t.h[3] = (bf16_t)a.w;
    t.h[4] = (bf16_t)b.x; t.h[5] = (bf16_t)b.y; t.h[6] = (bf16_t)b.z; t.h[7] = (bf16_t)b.w;
    *(uint4*)&xb[i] = t.u;
  } else {
    const uint4 z = {0u, 0u, 0u, 0u};
    for (int i = tid; i < znq; i += 256) zreg[i] = z;
  }
}

// ------------- 128x256 / BK=64 triple-buffer 1-barrier GEMM ---------------
// MODE 0: dense  h = xb @ W1t + b1, fused sent(h) epilogue.
// MODE 1: expert out[tok] = (gather(A,tok) @ We_t + be) * gate, cap-guarded.
// Sync invariants: stage(t+2)->buf[(t+2)%3], whose last reader (tile t-1)
// finished all ds_reads before the t-1-close barrier (reads feed MFMAs that
// precede it; sched_barrier(0) pins them). vmcnt(6) at tile-close => tile
// t+1 fully landed before any wave enters tile t+1. Prologue vmcnt(6) after
// 12; t=14 drains vmcnt(0); t=15 compute-only.
template <int MODE>
__global__ __launch_bounds__(512) void k_gemm256(
    const bf16_t* __restrict__ A, const bf16_t* __restrict__ Bt0,
    const float* __restrict__ bias0, bf16_t* __restrict__ out,
    float* __restrict__ sent, const int* __restrict__ tok,
    const int* __restrict__ cnt, const float* __restrict__ gate,
    const bf16_t* __restrict__ zp) {
  __shared__ alignas(16) bf16_t As[3][128 * 64];  // 48 KB
  __shared__ alignas(16) bf16_t Bs[3][256 * 64];  // 96 KB
  const int tid = threadIdx.x;
  const int lane = tid & 63, wave = tid >> 6;
  const int quad = lane >> 4, l15 = lane & 15;
  const int wm = wave >> 2, wn = wave & 3;  // 2M x 4N wave grid, 64x64/wave
  const int id = blockIdx.x;
  const int xcd = id & 7, rem = id >> 3;
  const int n0 = (rem & 3) * 256;

  int m0;
  int count = 0;
  const bf16_t* Bt;
  const float* bias;
  const int* tk = nullptr;
  if constexpr (MODE == 0) {
    m0 = (xcd * 16 + (rem >> 2)) * 128;  // XCD-contiguous: 1 batch per XCD
    Bt = Bt0;
    bias = bias0;
  } else {
    m0 = (rem >> 2) * 128;  // c0 within expert
    count = cnt[xcd];       // expert = XCD slot: weights L2-resident
    if (m0 >= count) return;
    Bt = Bt0 + (size_t)xcd * DIM * DIM;
    bias = bias0 + xcd * DIM;
    tk = tok + xcd * CAP;
  }

  const int kc = (tid & 7) ^ ((tid >> 3) & 7);  // pre-swizzled k-chunk
  const int rbase = tid >> 3;                   // 0..63; row&7 == rbase&7

  const bf16_t* gA[2];
  const bf16_t* gB[4];
#pragma unroll
  for (int i = 0; i < 2; i++) {
    const int r = i * 64 + rbase;
    if constexpr (MODE == 0) {
      gA[i] = A + (size_t)(m0 + r) * DIM + kc * 8;
    } else {
      const int ca = m0 + r;
      gA[i] = (ca < count) ? A + (size_t)tk[ca] * DIM + kc * 8 : zp;
    }
  }
#pragma unroll
  for (int i = 0; i < 4; i++)
    gB[i] = Bt + (size_t)(n0 + i * 64 + rbase) * DIM + kc * 8;

  auto stage = [&](int t, int bufi) {  // 6 gll16/thread = one full K-tile
#pragma unroll
    for (int i = 0; i < 2; i++)
      gll16(gA[i] + t * 64, &As[bufi][(i * 64 + wave * 8) * 64]);
#pragma unroll
    for (int i = 0; i < 4; i++)
      gll16(gB[i] + t * 64, &Bs[bufi][(i * 64 + wave * 8) * 64]);
  };

  fx4 acc[4][4];
#pragma unroll
  for (int i = 0; i < 4; i++)
#pragma unroll
    for (int j = 0; j < 4; j++) acc[i][j] = (fx4)0.0f;

  auto tilecomp = [&](int bufi) {  // 16 ds_read_b128 + 32 MFMA
    bf16x8 av[4][2], bv[4][2];
#pragma unroll
    for (int mf = 0; mf < 4; mf++)
#pragma unroll
      for (int s = 0; s < 2; s++)
        av[mf][s] = *(const bf16x8*)&As[bufi][(wm * 64 + mf * 16 + l15) * 64 +
                                             (((s * 4 + quad) ^ (l15 & 7)) << 3)];
#pragma unroll
    for (int nf = 0; nf < 4; nf++)
#pragma unroll
      for (int s = 0; s < 2; s++)
        bv[nf][s] = *(const bf16x8*)&Bs[bufi][(wn * 64 + nf * 16 + l15) * 64 +
                                             (((s * 4 + quad) ^ (l15 & 7)) << 3)];
    __builtin_amdgcn_s_setprio(1);
#pragma unroll
    for (int s = 0; s < 2; s++)
#pragma unroll
      for (int mf = 0; mf < 4; mf++)
#pragma unroll
        for (int nf = 0; nf < 4; nf++)
          acc[mf][nf] = __builtin_amdgcn_mfma_f32_16x16x32_bf16(
              av[mf][s], bv[nf][s], acc[mf][nf], 0, 0, 0);
    __builtin_amdgcn_s_setprio(0);
    __builtin_amdgcn_sched_barrier(0);  // pin reads+MFMA before the barrier
  };

  // prologue: tiles 0,1 staged; vmcnt(6) -> tile0 landed; barrier publishes
  stage(0, 0);
  stage(1, 1);
  VMC(6);
  BARRIER();

  int cur = 0;
#pragma unroll 1
  for (int t = 0; t < 14; t++) {
    int b2 = cur + 2;
    if (b2 >= 3) b2 -= 3;
    stage(t + 2, b2);   // overwrites tile t-1's buffer: reads done pre-barrier
    tilecomp(cur);
    VMC(6);             // tile t+1 fully landed (its 6 are oldest in queue)
    BARRIER();
    cur = cur + 1;
    if (cur == 3) cur = 0;
  }
  // t=14 (buf 2): nothing left to stage; drain tile 15 fully
  tilecomp(2);
  VMC(0);
  BARRIER();
  // t=15 (buf 0): compute-only
  tilecomp(0);

  // epilogue (C/D layout: col = l15, row = quad*4 + r  -- m89/m91)
  float bb[4];
#pragma unroll
  for (int nf = 0; nf < 4; nf++) bb[nf] = bias[n0 + wn * 64 + nf * 16 + l15];
  if constexpr (MODE == 0) {
    float sj[4] = {0.f, 0.f, 0.f, 0.f};
#pragma unroll
    for (int mf = 0; mf < 4; mf++)
#pragma unroll
      for (int r = 0; r < 4; r++) {
        const int rowL = wm * 64 + mf * 16 + quad * 4 + r;
#pragma unroll
        for (int nf = 0; nf < 4; nf++) {
          const float v = acc[mf][nf][r] + bb[nf];
          sj[nf] += v;
          out[(size_t)(m0 + rowL) * DIM + n0 + wn * 64 + nf * 16 + l15] = (bf16_t)v;
        }
      }
    // sent(h): block rows batch-uniform (m0 = xcd*2048 + mi*128)
#pragma unroll
    for (int nf = 0; nf < 4; nf++) {
      sj[nf] += __shfl_xor(sj[nf], 16);
      sj[nf] += __shfl_xor(sj[nf], 32);
    }
    if (quad == 0)
#pragma unroll
      for (int nf = 0; nf < 4; nf++)
        atomicAdd(&sent[(m0 >> 11) * DIM + n0 + wn * 64 + nf * 16 + l15],
                  sj[nf] * (1.0f / SEQ));
  } else {
#pragma unroll
    for (int mf = 0; mf < 4; mf++)
#pragma unroll
      for (int r = 0; r < 4; r++) {
        const int c = m0 + wm * 64 + mf * 16 + quad * 4 + r;
        if (c < count) {
          const int tkn = tk[c];
          const float g = gate[tkn];
#pragma unroll
          for (int nf = 0; nf < 4; nf++)
            out[(size_t)tkn * DIM + n0 + wn * 64 + nf * 16 + l15] =
                (bf16_t)((acc[mf][nf][r] + bb[nf]) * g);
        }
      }
  }
}

// ---------------- MFMA gating (r5-verified) --------------------------------
__global__ __launch_bounds__(256) void k_gate_mm(
    const bf16_t* __restrict__ act, const bf16_t* __restrict__ WgPx,
    int* __restrict__ idx, float* __restrict__ gate) {
  __shared__ alignas(16) bf16_t As[64 * 64];    // 8 KB
  __shared__ alignas(16) bf16_t WgS[128 * 64];  // 16 KB
  __shared__ float L[64][8];
  const int tid = threadIdx.x;
  const int lane = tid & 63, wave = tid >> 6;
  const int quad = lane >> 4, l15 = lane & 15;
  const int m0 = blockIdx.x * 64;
  const int kc = (tid & 7) ^ ((tid >> 3) & 7);
  const int rbase = tid >> 3;

#pragma unroll
  for (int j = 0; j < 4; j++)
    gll16(WgPx + (j * 256 + wave * 64 + lane) * 8, &WgS[(j * 256 + wave * 64) * 8]);

  const bf16_t* gA[2]; bf16_t* lA[2];
#pragma unroll
  for (int i = 0; i < 2; i++) {
    gA[i] = act + (size_t)(m0 + rbase + 32 * i) * DIM + kc * 8;
    lA[i] = &As[wave * 512 + i * 2048];
  }
  fx4 acc = (fx4)0.0f;
  for (int k0 = 0; k0 < DIM; k0 += 64) {
#pragma unroll
    for (int i = 0; i < 2; i++) gll16(gA[i] + k0, lA[i]);
    __syncthreads();
#pragma unroll
    for (int s = 0; s < 2; s++) {
      const int pofs = ((s * 4 + quad) ^ (l15 & 7)) << 3;
      bf16x8 av = *(const bf16x8*)&As[(wave * 16 + l15) * 64 + pofs];
      bf16x8 bv = *(const bf16x8*)&WgS[((k0 >> 3) + s * 4 + quad) * 64 + (l15 & 7) * 8];
      acc = __builtin_amdgcn_mfma_f32_16x16x32_bf16(av, bv, acc, 0, 0, 0);
    }
    __syncthreads();
  }
  if (l15 < 8) {
#pragma unroll
    for (int r = 0; r < 4; r++) L[wave * 16 + quad * 4 + r][l15] = acc[r];
  }
  __syncthreads();
  if (tid < 64) {
    float lg[8];
#pragma unroll
    for (int e = 0; e < 8; e++) lg[e] = L[tid][e];
    float best = lg[0];
    int bi = 0;
#pragma unroll
    for (int e = 1; e < 8; e++)
      if (lg[e] > best) { best = lg[e]; bi = e; }  // strict >: first max wins
    float s = 0.f;
#pragma unroll
    for (int e = 0; e < 8; e++) s += expf(lg[e] - best);
    idx[m0 + tid] = bi;
    gate[m0 + tid] = 1.0f / s;
  }
}

// ---------------- route: tok list + capacity drop + zero dropped rows ------
#define DLMAX 2048
__global__ __launch_bounds__(1024) void k_route(
    const int* __restrict__ idx, int* __restrict__ tok, int* __restrict__ cnt,
    bf16_t* __restrict__ obuf) {
  const int e = blockIdx.x;
  const int tid = threadIdx.x, lane = tid & 63, wv = tid >> 6;
  __shared__ int wsum[16];
  __shared__ int dlist[DLMAX];
  const int4* p = (const int4*)(idx + tid * 16);
  int m[16];
  int c = 0;
#pragma unroll
  for (int j = 0; j < 4; j++) {
    int4 v = p[j];
    m[j * 4 + 0] = (v.x == e);
    m[j * 4 + 1] = (v.y == e);
    m[j * 4 + 2] = (v.z == e);
    m[j * 4 + 3] = (v.w == e);
    c += m[j * 4] + m[j * 4 + 1] + m[j * 4 + 2] + m[j * 4 + 3];
  }
  int sc = c;  // intra-wave inclusive scan
#pragma unroll
  for (int off = 1; off < 64; off <<= 1) {
    int n = __shfl_up(sc, off);
    if (lane >= off) sc += n;
  }
  if (lane == 63) wsum[wv] = sc;
  __syncthreads();
  int wb = 0, tot = 0;
#pragma unroll
  for (int i = 0; i < 16; i++) {
    int s = wsum[i];
    tot += s;
    if (i < wv) wb += s;
  }
  int pos = wb + sc - c;  // exclusive prefix
  const uint4 z = {0u, 0u, 0u, 0u};
#pragma unroll
  for (int j = 0; j < 16; j++) {
    if (m[j]) {
      int t = tid * 16 + j;
      if (pos < CAP) {
        tok[e * CAP + pos] = t;
      } else {
        int di = pos - CAP;
        if (di < DLMAX) dlist[di] = t;
        else  // pathological overflow: zero directly
          for (int k = 0; k < 128; k++) *(uint4*)&obuf[(size_t)t * DIM + k * 8] = z;
      }
      pos++;
    }
  }
  if (tid == 0) cnt[e] = tot < CAP ? tot : CAP;
  __syncthreads();
  int ndl = tot - CAP;
  ndl = ndl < 0 ? 0 : (ndl > DLMAX ? DLMAX : ndl);
  for (int d = tid >> 7; d < ndl; d += 8) {  // 128 thr/row, 8 rows at a time
    int t = dlist[d];
    *(uint4*)&obuf[(size_t)t * DIM + (tid & 127) * 8] = z;
  }
}

// ---------------- reduce(o2): 3-level atomic-free tree + loss --------------
// L1: 1024 blocks, 16 rows each -> 1 partial row (LDS-combined halves).
// L2: last block per batch (done[b]==127) reduces 128 partials -> sentF[b].
// L3: last of 8 (done[8]) computes CE loss from sentF.
__global__ __launch_bounds__(256) void k_reduce_loss(
    const bf16_t* __restrict__ o2, const float* __restrict__ sent,
    float* __restrict__ sentP, float* __restrict__ sentF,
    const int* __restrict__ y, int* __restrict__ done,
    float* __restrict__ out) {
  const int tid = threadIdx.x;
  const int job = blockIdx.x;  // 1024 jobs: b = job>>7, chunk = job&127
  const int b = job >> 7;
  __shared__ float lds[2][DIM];
  {
    const int d8 = (tid & 127) * 8;
    const int sg = tid >> 7;
    const int s0 = (job & 127) * 16 + sg * 8;
    float acc[8] = {0.f, 0.f, 0.f, 0.f, 0.f, 0.f, 0.f, 0.f};
    const size_t base = ((size_t)b * SEQ + s0) * DIM + d8;
    uint4 u[8];  // 8 loads in flight
#pragma unroll
    for (int i = 0; i < 8; i++)
      u[i] = *(const uint4*)&o2[base + (size_t)i * DIM];
#pragma unroll
    for (int i = 0; i < 8; i++) {
      union { bf16_t v[8]; uint4 q; } oo;
      oo.q = u[i];
#pragma unroll
      for (int j = 0; j < 8; j++) acc[j] += (float)oo.v[j];
    }
#pragma unroll
    for (int j = 0; j < 8; j++) lds[sg][d8 + j] = acc[j];
  }
  __syncthreads();
  {  // combine halves -> one partial row per block (exclusive slot)
    const int c4 = tid * 4;
    float4 s;
    s.x = lds[0][c4] + lds[1][c4];
    s.y = lds[0][c4 + 1] + lds[1][c4 + 1];
    s.z = lds[0][c4 + 2] + lds[1][c4 + 2];
    s.w = lds[0][c4 + 3] + lds[1][c4 + 3];
    *(float4*)&sentP[(size_t)job * DIM + c4] = s;
  }
  // ---- L2: per-batch tail (8 concurrent) ----
  __shared__ int isLastB;
  __syncthreads();
  if (tid == 0) {
    __threadfence();  // release our sentP row
    isLastB = (atomicAdd(&done[b], 1) == 127);
  }
  __syncthreads();
  if (!isLastB) return;
  __threadfence();  // acquire batch's sentP rows
  {
    const int c4 = tid * 4;
    float4 t4 = {0.f, 0.f, 0.f, 0.f};
    const float* pb = sentP + (size_t)(b * 128) * DIM + c4;
#pragma unroll 1
    for (int r0 = 0; r0 < 128; r0 += 8) {
      float4 u[8];
#pragma unroll
      for (int r = 0; r < 8; r++) u[r] = *(const float4*)&pb[(size_t)(r0 + r) * DIM];
#pragma unroll
      for (int r = 0; r < 8; r++) {
        t4.x += u[r].x; t4.y += u[r].y; t4.z += u[r].z; t4.w += u[r].w;
      }
    }
    float4 s4 = *(const float4*)&sent[b * DIM + c4];  // dense-fused h part
    float4 f;
    f.x = s4.x + t4.x * (1.0f / SEQ);
    f.y = s4.y + t4.y * (1.0f / SEQ);
    f.z = s4.z + t4.z * (1.0f / SEQ);
    f.w = s4.w + t4.w * (1.0f / SEQ);
    *(float4*)&sentF[b * DIM + c4] = f;
  }
  // ---- L3: loss (1 block) ----
  __shared__ int isLastF;
  __syncthreads();
  if (tid == 0) {
    __threadfence();  // release sentF[b]
    isLastF = (atomicAdd(&done[8], 1) == 7);
  }
  __syncthreads();
  if (!isLastF) return;
  __threadfence();  // acquire all sentF rows
  __shared__ float red[256];
  float total = 0.f;
  for (int bb = 0; bb < BATCH; bb++) {
    const int c4 = tid * 4;
    float4 f = *(const float4*)&sentF[bb * DIM + c4];
    float m = fmaxf(fmaxf(f.x, f.y), fmaxf(f.z, f.w));
    red[tid] = m;
    __syncthreads();
    for (int s = 128; s; s >>= 1) {
      if (tid < s) red[tid] = fmaxf(red[tid], red[tid + s]);
      __syncthreads();
    }
    m = red[0];
    __syncthreads();
    float sum = expf(f.x - m) + expf(f.y - m) + expf(f.z - m) + expf(f.w - m);
    red[tid] = sum;
    __syncthreads();
    for (int s = 128; s; s >>= 1) {
      if (tid < s) red[tid] += red[tid + s];
      __syncthreads();
    }
    if (tid == 0) total += m + logf(red[0]) - sentF[bb * DIM + y[bb]];
    __syncthreads();
  }
  if (tid == 0) out[0] = total * (1.0f / BATCH);
}

// ---------------------------------------------------------------------------
extern "C" void kernel_launch(void* const* d_in, const int* in_sizes, int n_in,
                              void* d_out, int out_size, void* d_ws, size_t ws_size,
                              hipStream_t stream) {
  (void)in_sizes; (void)n_in; (void)out_size; (void)ws_size;
  const float* x   = (const float*)d_in[0];
  const int*   y   = (const int*)d_in[1];
  const float* W1  = (const float*)d_in[2];
  const float* b1  = (const float*)d_in[3];
  const float* Wg2 = (const float*)d_in[4];
  const float* We2 = (const float*)d_in[5];
  const float* be2 = (const float*)d_in[6];
  const float* Wg3 = (const float*)d_in[7];
  const float* We3 = (const float*)d_in[8];
  const float* be3 = (const float*)d_in[9];

  char* p = (char*)d_ws;
  size_t off = 0;
  auto carve = [&](size_t bytes) -> char* {
    char* r = p + off;
    off += (bytes + 255) & ~(size_t)255;
    return r;
  };
  bf16_t* Wt   = (bf16_t*)carve((size_t)17 * DIM * DIM * 2);  // 0:W1t 1..8:We2t 9..16:We3t
  bf16_t* WgP  = (bf16_t*)carve(2 * 128 * 8 * 8 * 2);         // gate B-frag packs
  bf16_t* h    = (bf16_t*)carve((size_t)TOKS * DIM * 2);
  bf16_t* o1   = (bf16_t*)carve((size_t)TOKS * DIM * 2);
  bf16_t* o2   = (bf16_t*)carve((size_t)TOKS * DIM * 2);  // aliases xb lifetime
  int*    idx  = (int*)carve(TOKS * 4);
  float*  gate = (float*)carve(TOKS * 4);
  int*    tok  = (int*)carve(NEXP * CAP * 4);
  int*    cnt  = (int*)carve(NEXP * 4);
  // --- contiguous zero region (filled by prep_x's last block) ---
  size_t zoff0 = off;
  float*  sent = (float*)carve(BATCH * DIM * 4);
  bf16_t* zp   = (bf16_t*)carve(4096);
  int*    done = (int*)carve(256);   // [0..7]: per-batch, [8]: final
  size_t zbytes = off - zoff0;
  // --- outside zero region: fully written before read, no zeroing needed ---
  float*  sentP = (float*)carve((size_t)1024 * DIM * 4);  // 4 MB L1 partials
  float*  sentF = (float*)carve((size_t)BATCH * DIM * 4);
  bf16_t* xb   = o2;  // x-bf16 dead before o2 is born (route3/expert3)

  // prep: weight transpose+cvt | Wg pack + x cvt + zero-fill
  k_prep_w<<<PW_BLOCKS, 256, 0, stream>>>(W1, We2, We3, Wt);
  k_prep_x<<<PREPX_GRID, 256, 0, stream>>>(
      Wg2, Wg3, x, WgP, xb, (uint4*)sent, (int)(zbytes / 16));

  // dense pre-layer (+ fused sent(h)): 128 x 4 tiles of 128x256 = 512 blocks
  k_gemm256<0><<<512, 512, 0, stream>>>(
      xb, Wt, b1, h, sent, nullptr, nullptr, nullptr, zp);

  // MoE layer 2
  k_gate_mm<<<TOKS / 64, 256, 0, stream>>>(h, WgP, idx, gate);
  k_route<<<NEXP, 1024, 0, stream>>>(idx, tok, cnt, o1);
  k_gemm256<1><<<512, 512, 0, stream>>>(
      h, Wt + (size_t)1 * DIM * DIM, be2, o1, nullptr, tok, cnt, gate, zp);

  // MoE layer 3
  k_gate_mm<<<TOKS / 64, 256, 0, stream>>>(o1, WgP + 128 * 8 * 8, idx, gate);
  k_route<<<NEXP, 1024, 0, stream>>>(idx, tok, cnt, o2);
  k_gemm256<1><<<512, 512, 0, stream>>>(
      o1, Wt + (size_t)9 * DIM * DIM, be3, o2, nullptr, tok, cnt, gate, zp);

  // 3-level reduce + loss -> d_out
  k_reduce_loss<<<1024, 256, 0, stream>>>(o2, sent, sentP, sentF, y, done,
                                          (float*)d_out);
}

// Round 7
// 414.384 us; speedup vs baseline: 1.0706x; 1.0706x over previous
//
#include <hip/hip_runtime.h>
#include <hip/hip_bf16.h>
#include <math.h>

// ---------------------------------------------------------------------------
// SimpleMoEModel: dense GEMM -> top1-MoE -> top1-MoE -> residual -> mean ->
// log_softmax -> NLL.  B=8 S=2048 D=1024 E=8, capacity = T/E = 2048.
//
// Round 18: r17 (443.6 us) double regression root-caused:
//  (a) reduce: done[] counters share ONE cacheline -> 1024 cross-XCD atomic
//      RMWs serialize (~50-100us). The counter tree WAS the reduce cost.
//  (b) triple-buffer GEMM: runtime buf indices defeat alias analysis ->
//      conservative vmcnt before ds_read bursts. Reverted to r13-verified
//      4-phase 256^2 (49.7 us measured).
// This round: o2 is consumed ONLY by the column-mean -> expert-3 GEMM gets
// MODE 2: skip the 32 MB o2 write; LDS-accumulate gated outputs into
// sacc[8][256] (ds_add, ~0.5us/block) and store one 8 KB slab per block
// (2 MB, non-atomic, disjoint; early-return blocks write zero slabs).
// k_sum (32 blocks, kernel-boundary sync, NO counter atomics) folds slabs +
// dense-fused sent -> sentF; k_loss (1 block) -> CE. Removes the 50-80 us
// handshake + 32 MB write + 32 MB read for ~8 us of new kernels.
// prep_w/prep_x/gate/route byte-identical to r16.
// ---------------------------------------------------------------------------

#define TOKS 16384
#define DIM 1024
#define NEXP 8
#define CAP 2048
#define BATCH 8
#define SEQ 2048

typedef __bf16 bf16_t;
typedef __bf16 bf16x8 __attribute__((ext_vector_type(8)));
typedef float fx4 __attribute__((ext_vector_type(4)));

__device__ __forceinline__ void gll16(const bf16_t* g, bf16_t* l) {
  __builtin_amdgcn_global_load_lds(
      (const __attribute__((address_space(1))) unsigned int*)g,
      (__attribute__((address_space(3))) unsigned int*)l, 16, 0, 0);
}

#define BARRIER() asm volatile("s_barrier" ::: "memory")
#define LGKM0()   asm volatile("s_waitcnt lgkmcnt(0)" ::: "memory")
#define VMC(N)    asm volatile("s_waitcnt vmcnt(" #N ")" ::: "memory")

// ---------------- prep A: weight transpose+cvt (17 x 1024^2) ---------------
#define PW_BLOCKS (17 * 64)
__global__ __launch_bounds__(256) void k_prep_w(
    const float* __restrict__ W1, const float* __restrict__ We2,
    const float* __restrict__ We3, bf16_t* __restrict__ Wt) {
  __shared__ bf16_t T[256][68];  // 34.8 KB; row stride 136 B (b64-aligned)
  const int id = blockIdx.x;
  const int tid = threadIdx.x;
  const int m = id >> 6, rem = id & 63;
  const int k0 = (rem >> 4) * 256, n0 = (rem & 15) * 64;
  const float* src = (m == 0) ? W1
                     : (m <= 8) ? We2 + (size_t)(m - 1) * DIM * DIM
                                : We3 + (size_t)(m - 9) * DIM * DIM;
  bf16_t* dst = Wt + (size_t)m * DIM * DIM;
  const int r = tid >> 4, nq = tid & 15;
#pragma unroll
  for (int i = 0; i < 16; i++) {
    const int k = i * 16 + r;
    float4 v = *(const float4*)&src[(size_t)(k0 + k) * DIM + n0 + nq * 4];
    union { bf16_t h[4]; uint2 u; } t;
    t.h[0] = (bf16_t)v.x; t.h[1] = (bf16_t)v.y;
    t.h[2] = (bf16_t)v.z; t.h[3] = (bf16_t)v.w;
    *(uint2*)&T[k][(nq ^ ((k >> 3) & 15)) << 2] = t.u;  // XOR col swizzle
  }
  __syncthreads();
#pragma unroll
  for (int p = 0; p < 8; p++) {
    const int idx2 = p * 256 + tid;
    const int nl = idx2 >> 5, ks = (idx2 & 31) * 8;
    union { bf16_t h[8]; uint4 u; } o;
#pragma unroll
    for (int j = 0; j < 8; j++) {
      const int k = ks + j;
      o.h[j] = T[k][((((nl >> 2) ^ ((k >> 3) & 15)) << 2) | (nl & 3))];
    }
    *(uint4*)&dst[(size_t)(n0 + nl) * DIM + k0 + ks] = o.u;
  }
}

// ---------------- prep B: Wg pack | x cvt | zero-fill ----------------------
#define CVT_BLOCKS (TOKS * DIM / 8 / 256)
#define PREPX_GRID (2 + CVT_BLOCKS + 1)
__global__ __launch_bounds__(256) void k_prep_x(
    const float* __restrict__ Wg2, const float* __restrict__ Wg3,
    const float* __restrict__ x, bf16_t* __restrict__ WgP,
    bf16_t* __restrict__ xb, uint4* __restrict__ zreg, int znq) {
  const int id = blockIdx.x;
  const int tid = threadIdx.x;
  if (id < 2) {
    const int which = id;
    const float* src = which ? Wg3 : Wg2;
    bf16_t* dst = WgP + which * (128 * 8 * 8);
#pragma unroll
    for (int j = 0; j < 4; j++) {
      int d = tid * 4 + j;
      float4 a = *(const float4*)&src[d * 8];
      float4 b = *(const float4*)&src[d * 8 + 4];
      float v[8] = {a.x, a.y, a.z, a.w, b.x, b.y, b.z, b.w};
#pragma unroll
      for (int e = 0; e < 8; e++)
        dst[((d >> 3) * 8 + e) * 8 + (d & 7)] = (bf16_t)v[e];
    }
  } else if (id < 2 + CVT_BLOCKS) {
    const int cid = id - 2;
    size_t i = ((size_t)cid * 256 + tid) * 8;
    float4 a = *(const float4*)&x[i];
    float4 b = *(const float4*)&x[i + 4];
    union { bf16_t h[8]; uint4 u; } t;
    t.h[0] = (bf16_t)a.x; t.h[1] = (bf16_t)a.y; t.h[2] = (bf16_t)a.z; t.h[3] = (bf16_t)a.w;
    t.h[4] = (bf16_t)b.x; t.h[5] = (bf16_t)b.y; t.h[6] = (bf16_t)b.z; t.h[7] = (bf16_t)b.w;
    *(uint4*)&xb[i] = t.u;
  } else {
    const uint4 z = {0u, 0u, 0u, 0u};
    for (int i = tid; i < znq; i += 256) zreg[i] = z;
  }
}

// ---------------- 256x256 / BK=64 4-phase GEMM (r13-verified) --------------
// MODE 0: dense  h = xb @ W1t + b1, fused sent(h) epilogue.
// MODE 1: expert out[tok] = (gather(A,tok) @ We_t + be) * gate, cap-guarded.
// MODE 2: expert, NO global out write; fused column-sum into slab (o2 is
//         only consumed by the mean -> slab[b][col] += (acc+bias)*gate).
template <int MODE>
__global__ __launch_bounds__(512) void k_gemm256(
    const bf16_t* __restrict__ A, const bf16_t* __restrict__ Bt0,
    const float* __restrict__ bias0, bf16_t* __restrict__ out,
    float* __restrict__ sent, const int* __restrict__ tok,
    const int* __restrict__ cnt, const float* __restrict__ gate,
    const bf16_t* __restrict__ zp, float* __restrict__ slabs) {
  __shared__ alignas(16) bf16_t As[2][256 * 64];  // 64 KB
  __shared__ alignas(16) bf16_t Bs[2][256 * 64];  // 64 KB
  __shared__ float sacc[MODE == 2 ? 8 * 256 : 1];
  const int tid = threadIdx.x;
  const int lane = tid & 63, wave = tid >> 6;
  const int quad = lane >> 4, l15 = lane & 15;
  const int wm = wave >> 2, wn = wave & 3;  // 2M x 4N wave grid
  const int id = blockIdx.x;
  const int xcd = id & 7, rem = id >> 3;
  const int n0 = (rem & 3) * 256;

  if constexpr (MODE == 2) {
    for (int i = tid; i < 2048; i += 512) sacc[i] = 0.f;
  }

  int m0;
  int count = 0;
  const bf16_t* Bt;
  const float* bias;
  const int* tk = nullptr;
  if constexpr (MODE == 0) {
    m0 = (xcd * 8 + (rem >> 2)) * 256;  // XCD-contiguous M stripes
    Bt = Bt0;
    bias = bias0;
  } else {
    m0 = (rem >> 2) * 256;  // c0 within expert
    count = cnt[xcd];       // expert = XCD slot: weights L2-resident
    if (m0 >= count) {
      if constexpr (MODE == 2) {  // slab must still be defined: zeros
        float* slab = slabs + (size_t)id * 2048;
        for (int i = tid; i < 2048; i += 512) slab[i] = 0.f;
      }
      return;
    }
    Bt = Bt0 + (size_t)xcd * DIM * DIM;
    bias = bias0 + xcd * DIM;
    tk = tok + xcd * CAP;
  }

  const int kc = (tid & 7) ^ ((tid >> 3) & 7);  // pre-swizzled k-chunk
  const int rbase = tid >> 3;                   // 0..63

  const bf16_t* gA[4];
  const bf16_t* gB[4];
#pragma unroll
  for (int h = 0; h < 2; h++)
#pragma unroll
    for (int i = 0; i < 2; i++) {
      const int r = h * 128 + i * 64 + rbase;  // row&7 == rbase&7
      if constexpr (MODE == 0) {
        gA[h * 2 + i] = A + (size_t)(m0 + r) * DIM + kc * 8;
      } else {
        const int ca = m0 + r;
        gA[h * 2 + i] = (ca < count) ? A + (size_t)tk[ca] * DIM + kc * 8 : zp;
      }
      gB[h * 2 + i] = Bt + (size_t)(n0 + r) * DIM + kc * 8;
    }

  auto stA = [&](int t, int half) {  // stage one A half-tile (2 gll/thread)
#pragma unroll
    for (int i = 0; i < 2; i++)
      gll16(gA[half * 2 + i] + t * 64,
            &As[t & 1][(half * 128 + i * 64 + wave * 8) * 64]);
  };
  auto stB = [&](int t, int half) {
#pragma unroll
    for (int i = 0; i < 2; i++)
      gll16(gB[half * 2 + i] + t * 64,
            &Bs[t & 1][(half * 128 + i * 64 + wave * 8) * 64]);
  };
  auto rdA = [&](bf16x8 (&av)[4][2], int buf, int mh) {
#pragma unroll
    for (int mf = 0; mf < 4; mf++)
#pragma unroll
      for (int s = 0; s < 2; s++)
        av[mf][s] = *(const bf16x8*)&As[buf][(wm * 128 + (mh * 4 + mf) * 16 + l15) * 64 +
                                            (((s * 4 + quad) ^ (l15 & 7)) << 3)];
  };
  auto rdB = [&](bf16x8 (&bv)[2][2], int buf, int nh) {
#pragma unroll
    for (int nf = 0; nf < 2; nf++)
#pragma unroll
      for (int s = 0; s < 2; s++)
        bv[nf][s] = *(const bf16x8*)&Bs[buf][(wn * 64 + (nh * 2 + nf) * 16 + l15) * 64 +
                                            (((s * 4 + quad) ^ (l15 & 7)) << 3)];
  };

  fx4 acc[8][4];
#pragma unroll
  for (int i = 0; i < 8; i++)
#pragma unroll
    for (int j = 0; j < 4; j++) acc[i][j] = (fx4)0.0f;

  auto mma = [&](bf16x8 (&av)[4][2], bf16x8 (&bv)[2][2], int mh, int nh) {
    __builtin_amdgcn_s_setprio(1);
#pragma unroll
    for (int s = 0; s < 2; s++)
#pragma unroll
      for (int mf = 0; mf < 4; mf++)
#pragma unroll
        for (int nf = 0; nf < 2; nf++)
          acc[mh * 4 + mf][nh * 2 + nf] = __builtin_amdgcn_mfma_f32_16x16x32_bf16(
              av[mf][s], bv[nf][s], acc[mh * 4 + mf][nh * 2 + nf], 0, 0, 0);
    __builtin_amdgcn_s_setprio(0);
  };

  // prologue: tile0 full; tile1 {B0,B1,A0} -> 3 half-tiles (6 ops) in flight
  stA(0, 0); stA(0, 1); stB(0, 0); stB(0, 1);
  stB(1, 0); stB(1, 1); stA(1, 0);
  VMC(6);   // tile0 fully landed (own ops); barrier publishes cross-wave
  BARRIER();

  bf16x8 av0[4][2], av1[4][2], bv0[2][2], bv1[2][2];
#pragma unroll 2
  for (int t = 0; t < 14; t++) {
    const int buf = t & 1;
    // P1: read av0 + ALL of B | stage A1(t+1) -> ~buf (always safe)
    rdA(av0, buf, 0); rdB(bv0, buf, 0); rdB(bv1, buf, 1);
    stA(t + 1, 1);
    BARRIER(); LGKM0();
    mma(av0, bv0, 0, 0);
    BARRIER();
    // P2: stage B0(t+2) -> buf (Bs[buf] fully read before P1-close)
    stB(t + 2, 0);
    BARRIER();
    mma(av0, bv1, 0, 1);
    BARRIER();
    // P3: read av1 | stage B1(t+2) -> buf
    rdA(av1, buf, 1);
    stB(t + 2, 1);
    BARRIER(); LGKM0();
    mma(av1, bv1, 1, 1);
    BARRIER();
    // P4: stage A0(t+2) -> buf (As[buf] fully read before P3-close)
    stA(t + 2, 0);
    mma(av1, bv0, 1, 0);
    VMC(6);   // newest 6 = {B0,B1,A0}(t+2); A1(t+1) and older landed
    BARRIER();
  }
  {  // t = 14 (buf=0): only A1(15) left to stage; drain fully for tile 15
    rdA(av0, 0, 0); rdB(bv0, 0, 0); rdB(bv1, 0, 1);
    stA(15, 1);
    BARRIER(); LGKM0();
    mma(av0, bv0, 0, 0);
    BARRIER();
    mma(av0, bv1, 0, 1);
    BARRIER();
    rdA(av1, 0, 1);
    BARRIER(); LGKM0();
    mma(av1, bv1, 1, 1);
    BARRIER();
    mma(av1, bv0, 1, 0);
    VMC(0);
    BARRIER();
  }
  {  // t = 15 (buf=1): compute-only tail
    rdA(av0, 1, 0); rdB(bv0, 1, 0); rdB(bv1, 1, 1); rdA(av1, 1, 1);
    LGKM0();
    mma(av0, bv0, 0, 0); mma(av0, bv1, 0, 1);
    mma(av1, bv1, 1, 1); mma(av1, bv0, 1, 0);
  }

  // epilogue (C/D layout: col = l15, row = quad*4 + r  -- m89/m91)
  float bb[4];
#pragma unroll
  for (int nf = 0; nf < 4; nf++) bb[nf] = bias[n0 + wn * 64 + nf * 16 + l15];
  if constexpr (MODE == 0) {
    float sj[4] = {0.f, 0.f, 0.f, 0.f};
#pragma unroll
    for (int mf = 0; mf < 8; mf++)
#pragma unroll
      for (int r = 0; r < 4; r++) {
        const int rowL = wm * 128 + mf * 16 + quad * 4 + r;
#pragma unroll
        for (int nf = 0; nf < 4; nf++) {
          const float v = acc[mf][nf][r] + bb[nf];
          sj[nf] += v;
          out[(size_t)(m0 + rowL) * DIM + n0 + wn * 64 + nf * 16 + l15] = (bf16_t)v;
        }
      }
    // sent(h): block rows are batch-uniform (m0 % 256 == 0, SEQ % 256 == 0)
#pragma unroll
    for (int nf = 0; nf < 4; nf++) {
      sj[nf] += __shfl_xor(sj[nf], 16);
      sj[nf] += __shfl_xor(sj[nf], 32);
    }
    if (quad == 0)
#pragma unroll
      for (int nf = 0; nf < 4; nf++)
        atomicAdd(&sent[(m0 >> 11) * DIM + n0 + wn * 64 + nf * 16 + l15],
                  sj[nf] * (1.0f / SEQ));
  } else if constexpr (MODE == 1) {
#pragma unroll
    for (int mf = 0; mf < 8; mf++)
#pragma unroll
      for (int r = 0; r < 4; r++) {
        const int c = m0 + wm * 128 + mf * 16 + quad * 4 + r;
        if (c < count) {
          const int tkn = tk[c];
          const float g = gate[tkn];
#pragma unroll
          for (int nf = 0; nf < 4; nf++)
            out[(size_t)tkn * DIM + n0 + wn * 64 + nf * 16 + l15] =
                (bf16_t)((acc[mf][nf][r] + bb[nf]) * g);
        }
      }
  } else {
    // MODE 2: fused column-sum; no o2 write. sacc zeroed at entry; many
    // barriers since. LDS atomics only (no device atomics).
#pragma unroll
    for (int mf = 0; mf < 8; mf++)
#pragma unroll
      for (int r = 0; r < 4; r++) {
        const int c = m0 + wm * 128 + mf * 16 + quad * 4 + r;
        if (c < count) {
          const int tkn = tk[c];
          const float g = gate[tkn];
          const int b = tkn >> 11;  // SEQ = 2048
#pragma unroll
          for (int nf = 0; nf < 4; nf++)
            atomicAdd(&sacc[b * 256 + wn * 64 + nf * 16 + l15],
                      (acc[mf][nf][r] + bb[nf]) * g);
        }
      }
    __syncthreads();
    float* slab = slabs + (size_t)id * 2048;
    for (int i = tid; i < 2048; i += 512) slab[i] = sacc[i];
  }
}

// ---------------- MFMA gating (r5-verified) --------------------------------
__global__ __launch_bounds__(256) void k_gate_mm(
    const bf16_t* __restrict__ act, const bf16_t* __restrict__ WgPx,
    int* __restrict__ idx, float* __restrict__ gate) {
  __shared__ alignas(16) bf16_t As[64 * 64];    // 8 KB
  __shared__ alignas(16) bf16_t WgS[128 * 64];  // 16 KB
  __shared__ float L[64][8];
  const int tid = threadIdx.x;
  const int lane = tid & 63, wave = tid >> 6;
  const int quad = lane >> 4, l15 = lane & 15;
  const int m0 = blockIdx.x * 64;
  const int kc = (tid & 7) ^ ((tid >> 3) & 7);
  const int rbase = tid >> 3;

#pragma unroll
  for (int j = 0; j < 4; j++)
    gll16(WgPx + (j * 256 + wave * 64 + lane) * 8, &WgS[(j * 256 + wave * 64) * 8]);

  const bf16_t* gA[2]; bf16_t* lA[2];
#pragma unroll
  for (int i = 0; i < 2; i++) {
    gA[i] = act + (size_t)(m0 + rbase + 32 * i) * DIM + kc * 8;
    lA[i] = &As[wave * 512 + i * 2048];
  }
  fx4 acc = (fx4)0.0f;
  for (int k0 = 0; k0 < DIM; k0 += 64) {
#pragma unroll
    for (int i = 0; i < 2; i++) gll16(gA[i] + k0, lA[i]);
    __syncthreads();
#pragma unroll
    for (int s = 0; s < 2; s++) {
      const int pofs = ((s * 4 + quad) ^ (l15 & 7)) << 3;
      bf16x8 av = *(const bf16x8*)&As[(wave * 16 + l15) * 64 + pofs];
      bf16x8 bv = *(const bf16x8*)&WgS[((k0 >> 3) + s * 4 + quad) * 64 + (l15 & 7) * 8];
      acc = __builtin_amdgcn_mfma_f32_16x16x32_bf16(av, bv, acc, 0, 0, 0);
    }
    __syncthreads();
  }
  if (l15 < 8) {
#pragma unroll
    for (int r = 0; r < 4; r++) L[wave * 16 + quad * 4 + r][l15] = acc[r];
  }
  __syncthreads();
  if (tid < 64) {
    float lg[8];
#pragma unroll
    for (int e = 0; e < 8; e++) lg[e] = L[tid][e];
    float best = lg[0];
    int bi = 0;
#pragma unroll
    for (int e = 1; e < 8; e++)
      if (lg[e] > best) { best = lg[e]; bi = e; }  // strict >: first max wins
    float s = 0.f;
#pragma unroll
    for (int e = 0; e < 8; e++) s += expf(lg[e] - best);
    idx[m0 + tid] = bi;
    gate[m0 + tid] = 1.0f / s;
  }
}

// ---------------- route: tok list + capacity drop + zero dropped rows ------
#define DLMAX 2048
__global__ __launch_bounds__(1024) void k_route(
    const int* __restrict__ idx, int* __restrict__ tok, int* __restrict__ cnt,
    bf16_t* __restrict__ obuf) {
  const int e = blockIdx.x;
  const int tid = threadIdx.x, lane = tid & 63, wv = tid >> 6;
  __shared__ int wsum[16];
  __shared__ int dlist[DLMAX];
  const int4* p = (const int4*)(idx + tid * 16);
  int m[16];
  int c = 0;
#pragma unroll
  for (int j = 0; j < 4; j++) {
    int4 v = p[j];
    m[j * 4 + 0] = (v.x == e);
    m[j * 4 + 1] = (v.y == e);
    m[j * 4 + 2] = (v.z == e);
    m[j * 4 + 3] = (v.w == e);
    c += m[j * 4] + m[j * 4 + 1] + m[j * 4 + 2] + m[j * 4 + 3];
  }
  int sc = c;  // intra-wave inclusive scan
#pragma unroll
  for (int off = 1; off < 64; off <<= 1) {
    int n = __shfl_up(sc, off);
    if (lane >= off) sc += n;
  }
  if (lane == 63) wsum[wv] = sc;
  __syncthreads();
  int wb = 0, tot = 0;
#pragma unroll
  for (int i = 0; i < 16; i++) {
    int s = wsum[i];
    tot += s;
    if (i < wv) wb += s;
  }
  int pos = wb + sc - c;  // exclusive prefix
  const uint4 z = {0u, 0u, 0u, 0u};
#pragma unroll
  for (int j = 0; j < 16; j++) {
    if (m[j]) {
      int t = tid * 16 + j;
      if (pos < CAP) {
        tok[e * CAP + pos] = t;
      } else {
        int di = pos - CAP;
        if (di < DLMAX) dlist[di] = t;
        else  // pathological overflow: zero directly
          for (int k = 0; k < 128; k++) *(uint4*)&obuf[(size_t)t * DIM + k * 8] = z;
      }
      pos++;
    }
  }
  if (tid == 0) cnt[e] = tot < CAP ? tot : CAP;
  __syncthreads();
  int ndl = tot - CAP;
  ndl = ndl < 0 ? 0 : (ndl > DLMAX ? DLMAX : ndl);
  for (int d = tid >> 7; d < ndl; d += 8) {  // 128 thr/row, 8 rows at a time
    int t = dlist[d];
    *(uint4*)&obuf[(size_t)t * DIM + (tid & 127) * 8] = z;
  }
}

// ---------------- k_sum: slabs + sent(h) -> sentF (no atomics) -------------
// grid 32: b = bid>>2, sub(ntile) = bid&3. slab id = rem*8+xcd, ntile=rem&3.
__global__ __launch_bounds__(256) void k_sum(
    const float* __restrict__ slabs, const float* __restrict__ sent,
    float* __restrict__ sentF) {
  const int b = blockIdx.x >> 2, sub = blockIdx.x & 3;
  const int tid = threadIdx.x;
  float a = 0.f;
#pragma unroll 1
  for (int rg = 0; rg < 8; rg++) {
    const int rem = rg * 4 + sub;
#pragma unroll
    for (int xcd = 0; xcd < 8; xcd++)
      a += slabs[(size_t)(rem * 8 + xcd) * 2048 + b * 256 + tid];
  }
  const int col = sub * 256 + tid;
  sentF[b * DIM + col] = sent[b * DIM + col] + a * (1.0f / SEQ);
}

// ---------------- k_loss: CE from sentF (1 block) --------------------------
__global__ __launch_bounds__(256) void k_loss(
    const float* __restrict__ sentF, const int* __restrict__ y,
    float* __restrict__ out) {
  const int tid = threadIdx.x;
  __shared__ float red[256];
  float total = 0.f;
  for (int b = 0; b < BATCH; b++) {
    const int c4 = tid * 4;
    float4 f = *(const float4*)&sentF[b * DIM + c4];
    float m = fmaxf(fmaxf(f.x, f.y), fmaxf(f.z, f.w));
    red[tid] = m;
    __syncthreads();
    for (int s = 128; s; s >>= 1) {
      if (tid < s) red[tid] = fmaxf(red[tid], red[tid + s]);
      __syncthreads();
    }
    m = red[0];
    __syncthreads();
    float sum = expf(f.x - m) + expf(f.y - m) + expf(f.z - m) + expf(f.w - m);
    red[tid] = sum;
    __syncthreads();
    for (int s = 128; s; s >>= 1) {
      if (tid < s) red[tid] += red[tid + s];
      __syncthreads();
    }
    if (tid == 0) total += m + logf(red[0]) - sentF[b * DIM + y[b]];
    __syncthreads();
  }
  if (tid == 0) out[0] = total * (1.0f / BATCH);
}

// ---------------------------------------------------------------------------
extern "C" void kernel_launch(void* const* d_in, const int* in_sizes, int n_in,
                              void* d_out, int out_size, void* d_ws, size_t ws_size,
                              hipStream_t stream) {
  (void)in_sizes; (void)n_in; (void)out_size; (void)ws_size;
  const float* x   = (const float*)d_in[0];
  const int*   y   = (const int*)d_in[1];
  const float* W1  = (const float*)d_in[2];
  const float* b1  = (const float*)d_in[3];
  const float* Wg2 = (const float*)d_in[4];
  const float* We2 = (const float*)d_in[5];
  const float* be2 = (const float*)d_in[6];
  const float* Wg3 = (const float*)d_in[7];
  const float* We3 = (const float*)d_in[8];
  const float* be3 = (const float*)d_in[9];

  char* p = (char*)d_ws;
  size_t off = 0;
  auto carve = [&](size_t bytes) -> char* {
    char* r = p + off;
    off += (bytes + 255) & ~(size_t)255;
    return r;
  };
  bf16_t* Wt   = (bf16_t*)carve((size_t)17 * DIM * DIM * 2);  // 0:W1t 1..8:We2t 9..16:We3t
  bf16_t* WgP  = (bf16_t*)carve(2 * 128 * 8 * 8 * 2);         // gate B-frag packs
  bf16_t* h    = (bf16_t*)carve((size_t)TOKS * DIM * 2);
  bf16_t* o1   = (bf16_t*)carve((size_t)TOKS * DIM * 2);
  bf16_t* o2   = (bf16_t*)carve((size_t)TOKS * DIM * 2);  // aliases xb lifetime
  int*    idx  = (int*)carve(TOKS * 4);
  float*  gate = (float*)carve(TOKS * 4);
  int*    tok  = (int*)carve(NEXP * CAP * 4);
  int*    cnt  = (int*)carve(NEXP * 4);
  // --- contiguous zero region (filled by prep_x's last block) ---
  size_t zoff0 = off;
  float*  sent = (float*)carve(BATCH * DIM * 4);
  bf16_t* zp   = (bf16_t*)carve(4096);
  size_t zbytes = off - zoff0;
  // --- outside zero region: fully written before read, no zeroing needed ---
  float*  slabs = (float*)carve((size_t)256 * 2048 * 4);  // 2 MB MODE2 slabs
  float*  sentF = (float*)carve((size_t)BATCH * DIM * 4);
  bf16_t* xb   = o2;  // x-bf16 dead before o2 is born (route3)

  // prep: weight transpose+cvt | Wg pack + x cvt + zero-fill
  k_prep_w<<<PW_BLOCKS, 256, 0, stream>>>(W1, We2, We3, Wt);
  k_prep_x<<<PREPX_GRID, 256, 0, stream>>>(
      Wg2, Wg3, x, WgP, xb, (uint4*)sent, (int)(zbytes / 16));

  // dense pre-layer (+ fused sent(h)): 64 x 4 tiles of 256^2 = 256 blocks
  k_gemm256<0><<<256, 512, 0, stream>>>(
      xb, Wt, b1, h, sent, nullptr, nullptr, nullptr, zp, nullptr);

  // MoE layer 2
  k_gate_mm<<<TOKS / 64, 256, 0, stream>>>(h, WgP, idx, gate);
  k_route<<<NEXP, 1024, 0, stream>>>(idx, tok, cnt, o1);
  k_gemm256<1><<<256, 512, 0, stream>>>(
      h, Wt + (size_t)1 * DIM * DIM, be2, o1, nullptr, tok, cnt, gate, zp, nullptr);

  // MoE layer 3 (expert output never materialized: fused column-sum)
  k_gate_mm<<<TOKS / 64, 256, 0, stream>>>(o1, WgP + 128 * 8 * 8, idx, gate);
  k_route<<<NEXP, 1024, 0, stream>>>(idx, tok, cnt, o2);
  k_gemm256<2><<<256, 512, 0, stream>>>(
      o1, Wt + (size_t)9 * DIM * DIM, be3, nullptr, nullptr, tok, cnt, gate, zp, slabs);

  // slabs + sent -> sentF -> CE loss (kernel-boundary sync, no counters)
  k_sum<<<32, 256, 0, stream>>>(slabs, sent, sentF);
  k_loss<<<1, 256, 0, stream>>>(sentF, y, (float*)d_out);
}

// Round 8
// 351.815 us; speedup vs baseline: 1.2610x; 1.1778x over previous
//
#include <hip/hip_runtime.h>
#include <hip/hip_bf16.h>
#include <math.h>

// ---------------------------------------------------------------------------
// SimpleMoEModel: dense GEMM -> top1-MoE -> top1-MoE -> residual -> mean ->
// log_softmax -> NLL.  B=8 S=2048 D=1024 E=8, capacity = T/E = 2048.
//
// Round 19: r18 (414.4 us) regression root-caused: MODE2's fused column-sum
// used atomicAdd on LDS float -> CAS retry loop (no native f32 LDS atomic
// emitted) x 4-way same-address contention x 65536 lane-ops = ~66 us/block
// (MfmaUtil exactly halved; bank-conflict counter 0 -- same-address retries,
// not bank aliasing).
// Fix: zero-atomic epilogue. b has 8 values -> REGISTER buckets with static
// indexing (rule #20): colacc[4][8] (+32 VGPR), predicated adds; shfl_xor
// 16/32 folds quads; quad0 lanes write per-wm slices into LDS OVERLAID on
// the dead As buffer (post-syncthreads, non-atomic, 1 writer/address);
// block emits one 8 KB slab. LDS stays 128 KB.
// Everything else byte-identical to r18 (4-phase GEMM, k_sum/k_loss tree).
// ---------------------------------------------------------------------------

#define TOKS 16384
#define DIM 1024
#define NEXP 8
#define CAP 2048
#define BATCH 8
#define SEQ 2048

typedef __bf16 bf16_t;
typedef __bf16 bf16x8 __attribute__((ext_vector_type(8)));
typedef float fx4 __attribute__((ext_vector_type(4)));

__device__ __forceinline__ void gll16(const bf16_t* g, bf16_t* l) {
  __builtin_amdgcn_global_load_lds(
      (const __attribute__((address_space(1))) unsigned int*)g,
      (__attribute__((address_space(3))) unsigned int*)l, 16, 0, 0);
}

#define BARRIER() asm volatile("s_barrier" ::: "memory")
#define LGKM0()   asm volatile("s_waitcnt lgkmcnt(0)" ::: "memory")
#define VMC(N)    asm volatile("s_waitcnt vmcnt(" #N ")" ::: "memory")

// ---------------- prep A: weight transpose+cvt (17 x 1024^2) ---------------
#define PW_BLOCKS (17 * 64)
__global__ __launch_bounds__(256) void k_prep_w(
    const float* __restrict__ W1, const float* __restrict__ We2,
    const float* __restrict__ We3, bf16_t* __restrict__ Wt) {
  __shared__ bf16_t T[256][68];  // 34.8 KB; row stride 136 B (b64-aligned)
  const int id = blockIdx.x;
  const int tid = threadIdx.x;
  const int m = id >> 6, rem = id & 63;
  const int k0 = (rem >> 4) * 256, n0 = (rem & 15) * 64;
  const float* src = (m == 0) ? W1
                     : (m <= 8) ? We2 + (size_t)(m - 1) * DIM * DIM
                                : We3 + (size_t)(m - 9) * DIM * DIM;
  bf16_t* dst = Wt + (size_t)m * DIM * DIM;
  const int r = tid >> 4, nq = tid & 15;
#pragma unroll
  for (int i = 0; i < 16; i++) {
    const int k = i * 16 + r;
    float4 v = *(const float4*)&src[(size_t)(k0 + k) * DIM + n0 + nq * 4];
    union { bf16_t h[4]; uint2 u; } t;
    t.h[0] = (bf16_t)v.x; t.h[1] = (bf16_t)v.y;
    t.h[2] = (bf16_t)v.z; t.h[3] = (bf16_t)v.w;
    *(uint2*)&T[k][(nq ^ ((k >> 3) & 15)) << 2] = t.u;  // XOR col swizzle
  }
  __syncthreads();
#pragma unroll
  for (int p = 0; p < 8; p++) {
    const int idx2 = p * 256 + tid;
    const int nl = idx2 >> 5, ks = (idx2 & 31) * 8;
    union { bf16_t h[8]; uint4 u; } o;
#pragma unroll
    for (int j = 0; j < 8; j++) {
      const int k = ks + j;
      o.h[j] = T[k][((((nl >> 2) ^ ((k >> 3) & 15)) << 2) | (nl & 3))];
    }
    *(uint4*)&dst[(size_t)(n0 + nl) * DIM + k0 + ks] = o.u;
  }
}

// ---------------- prep B: Wg pack | x cvt | zero-fill ----------------------
#define CVT_BLOCKS (TOKS * DIM / 8 / 256)
#define PREPX_GRID (2 + CVT_BLOCKS + 1)
__global__ __launch_bounds__(256) void k_prep_x(
    const float* __restrict__ Wg2, const float* __restrict__ Wg3,
    const float* __restrict__ x, bf16_t* __restrict__ WgP,
    bf16_t* __restrict__ xb, uint4* __restrict__ zreg, int znq) {
  const int id = blockIdx.x;
  const int tid = threadIdx.x;
  if (id < 2) {
    const int which = id;
    const float* src = which ? Wg3 : Wg2;
    bf16_t* dst = WgP + which * (128 * 8 * 8);
#pragma unroll
    for (int j = 0; j < 4; j++) {
      int d = tid * 4 + j;
      float4 a = *(const float4*)&src[d * 8];
      float4 b = *(const float4*)&src[d * 8 + 4];
      float v[8] = {a.x, a.y, a.z, a.w, b.x, b.y, b.z, b.w};
#pragma unroll
      for (int e = 0; e < 8; e++)
        dst[((d >> 3) * 8 + e) * 8 + (d & 7)] = (bf16_t)v[e];
    }
  } else if (id < 2 + CVT_BLOCKS) {
    const int cid = id - 2;
    size_t i = ((size_t)cid * 256 + tid) * 8;
    float4 a = *(const float4*)&x[i];
    float4 b = *(const float4*)&x[i + 4];
    union { bf16_t h[8]; uint4 u; } t;
    t.h[0] = (bf16_t)a.x; t.h[1] = (bf16_t)a.y; t.h[2] = (bf16_t)a.z; t.h[3] = (bf16_t)a.w;
    t.h[4] = (bf16_t)b.x; t.h[5] = (bf16_t)b.y; t.h[6] = (bf16_t)b.z; t.h[7] = (bf16_t)b.w;
    *(uint4*)&xb[i] = t.u;
  } else {
    const uint4 z = {0u, 0u, 0u, 0u};
    for (int i = tid; i < znq; i += 256) zreg[i] = z;
  }
}

// ---------------- 256x256 / BK=64 4-phase GEMM (r13-verified) --------------
// MODE 0: dense  h = xb @ W1t + b1, fused sent(h) epilogue.
// MODE 1: expert out[tok] = (gather(A,tok) @ We_t + be) * gate, cap-guarded.
// MODE 2: expert, NO o2 write; register-bucket column-sum -> 8 KB slab.
template <int MODE>
__global__ __launch_bounds__(512) void k_gemm256(
    const bf16_t* __restrict__ A, const bf16_t* __restrict__ Bt0,
    const float* __restrict__ bias0, bf16_t* __restrict__ out,
    float* __restrict__ sent, const int* __restrict__ tok,
    const int* __restrict__ cnt, const float* __restrict__ gate,
    const bf16_t* __restrict__ zp, float* __restrict__ slabs) {
  __shared__ alignas(16) bf16_t As[2][256 * 64];  // 64 KB
  __shared__ alignas(16) bf16_t Bs[2][256 * 64];  // 64 KB
  const int tid = threadIdx.x;
  const int lane = tid & 63, wave = tid >> 6;
  const int quad = lane >> 4, l15 = lane & 15;
  const int wm = wave >> 2, wn = wave & 3;  // 2M x 4N wave grid
  const int id = blockIdx.x;
  const int xcd = id & 7, rem = id >> 3;
  const int n0 = (rem & 3) * 256;

  int m0;
  int count = 0;
  const bf16_t* Bt;
  const float* bias;
  const int* tk = nullptr;
  if constexpr (MODE == 0) {
    m0 = (xcd * 8 + (rem >> 2)) * 256;  // XCD-contiguous M stripes
    Bt = Bt0;
    bias = bias0;
  } else {
    m0 = (rem >> 2) * 256;  // c0 within expert
    count = cnt[xcd];       // expert = XCD slot: weights L2-resident
    if (m0 >= count) {
      if constexpr (MODE == 2) {  // slab must still be defined: zeros
        float* slab = slabs + (size_t)id * 2048;
        for (int i = tid; i < 2048; i += 512) slab[i] = 0.f;
      }
      return;
    }
    Bt = Bt0 + (size_t)xcd * DIM * DIM;
    bias = bias0 + xcd * DIM;
    tk = tok + xcd * CAP;
  }

  const int kc = (tid & 7) ^ ((tid >> 3) & 7);  // pre-swizzled k-chunk
  const int rbase = tid >> 3;                   // 0..63

  const bf16_t* gA[4];
  const bf16_t* gB[4];
#pragma unroll
  for (int h = 0; h < 2; h++)
#pragma unroll
    for (int i = 0; i < 2; i++) {
      const int r = h * 128 + i * 64 + rbase;  // row&7 == rbase&7
      if constexpr (MODE == 0) {
        gA[h * 2 + i] = A + (size_t)(m0 + r) * DIM + kc * 8;
      } else {
        const int ca = m0 + r;
        gA[h * 2 + i] = (ca < count) ? A + (size_t)tk[ca] * DIM + kc * 8 : zp;
      }
      gB[h * 2 + i] = Bt + (size_t)(n0 + r) * DIM + kc * 8;
    }

  auto stA = [&](int t, int half) {  // stage one A half-tile (2 gll/thread)
#pragma unroll
    for (int i = 0; i < 2; i++)
      gll16(gA[half * 2 + i] + t * 64,
            &As[t & 1][(half * 128 + i * 64 + wave * 8) * 64]);
  };
  auto stB = [&](int t, int half) {
#pragma unroll
    for (int i = 0; i < 2; i++)
      gll16(gB[half * 2 + i] + t * 64,
            &Bs[t & 1][(half * 128 + i * 64 + wave * 8) * 64]);
  };
  auto rdA = [&](bf16x8 (&av)[4][2], int buf, int mh) {
#pragma unroll
    for (int mf = 0; mf < 4; mf++)
#pragma unroll
      for (int s = 0; s < 2; s++)
        av[mf][s] = *(const bf16x8*)&As[buf][(wm * 128 + (mh * 4 + mf) * 16 + l15) * 64 +
                                            (((s * 4 + quad) ^ (l15 & 7)) << 3)];
  };
  auto rdB = [&](bf16x8 (&bv)[2][2], int buf, int nh) {
#pragma unroll
    for (int nf = 0; nf < 2; nf++)
#pragma unroll
      for (int s = 0; s < 2; s++)
        bv[nf][s] = *(const bf16x8*)&Bs[buf][(wn * 64 + (nh * 2 + nf) * 16 + l15) * 64 +
                                            (((s * 4 + quad) ^ (l15 & 7)) << 3)];
  };

  fx4 acc[8][4];
#pragma unroll
  for (int i = 0; i < 8; i++)
#pragma unroll
    for (int j = 0; j < 4; j++) acc[i][j] = (fx4)0.0f;

  auto mma = [&](bf16x8 (&av)[4][2], bf16x8 (&bv)[2][2], int mh, int nh) {
    __builtin_amdgcn_s_setprio(1);
#pragma unroll
    for (int s = 0; s < 2; s++)
#pragma unroll
      for (int mf = 0; mf < 4; mf++)
#pragma unroll
        for (int nf = 0; nf < 2; nf++)
          acc[mh * 4 + mf][nh * 2 + nf] = __builtin_amdgcn_mfma_f32_16x16x32_bf16(
              av[mf][s], bv[nf][s], acc[mh * 4 + mf][nh * 2 + nf], 0, 0, 0);
    __builtin_amdgcn_s_setprio(0);
  };

  // prologue: tile0 full; tile1 {B0,B1,A0} -> 3 half-tiles (6 ops) in flight
  stA(0, 0); stA(0, 1); stB(0, 0); stB(0, 1);
  stB(1, 0); stB(1, 1); stA(1, 0);
  VMC(6);   // tile0 fully landed (own ops); barrier publishes cross-wave
  BARRIER();

  bf16x8 av0[4][2], av1[4][2], bv0[2][2], bv1[2][2];
#pragma unroll 2
  for (int t = 0; t < 14; t++) {
    const int buf = t & 1;
    // P1: read av0 + ALL of B | stage A1(t+1) -> ~buf (always safe)
    rdA(av0, buf, 0); rdB(bv0, buf, 0); rdB(bv1, buf, 1);
    stA(t + 1, 1);
    BARRIER(); LGKM0();
    mma(av0, bv0, 0, 0);
    BARRIER();
    // P2: stage B0(t+2) -> buf (Bs[buf] fully read before P1-close)
    stB(t + 2, 0);
    BARRIER();
    mma(av0, bv1, 0, 1);
    BARRIER();
    // P3: read av1 | stage B1(t+2) -> buf
    rdA(av1, buf, 1);
    stB(t + 2, 1);
    BARRIER(); LGKM0();
    mma(av1, bv1, 1, 1);
    BARRIER();
    // P4: stage A0(t+2) -> buf (As[buf] fully read before P3-close)
    stA(t + 2, 0);
    mma(av1, bv0, 1, 0);
    VMC(6);   // newest 6 = {B0,B1,A0}(t+2); A1(t+1) and older landed
    BARRIER();
  }
  {  // t = 14 (buf=0): only A1(15) left to stage; drain fully for tile 15
    rdA(av0, 0, 0); rdB(bv0, 0, 0); rdB(bv1, 0, 1);
    stA(15, 1);
    BARRIER(); LGKM0();
    mma(av0, bv0, 0, 0);
    BARRIER();
    mma(av0, bv1, 0, 1);
    BARRIER();
    rdA(av1, 0, 1);
    BARRIER(); LGKM0();
    mma(av1, bv1, 1, 1);
    BARRIER();
    mma(av1, bv0, 1, 0);
    VMC(0);
    BARRIER();
  }
  {  // t = 15 (buf=1): compute-only tail
    rdA(av0, 1, 0); rdB(bv0, 1, 0); rdB(bv1, 1, 1); rdA(av1, 1, 1);
    LGKM0();
    mma(av0, bv0, 0, 0); mma(av0, bv1, 0, 1);
    mma(av1, bv1, 1, 1); mma(av1, bv0, 1, 0);
  }

  // epilogue (C/D layout: col = l15, row = quad*4 + r  -- m89/m91)
  float bb[4];
#pragma unroll
  for (int nf = 0; nf < 4; nf++) bb[nf] = bias[n0 + wn * 64 + nf * 16 + l15];
  if constexpr (MODE == 0) {
    float sj[4] = {0.f, 0.f, 0.f, 0.f};
#pragma unroll
    for (int mf = 0; mf < 8; mf++)
#pragma unroll
      for (int r = 0; r < 4; r++) {
        const int rowL = wm * 128 + mf * 16 + quad * 4 + r;
#pragma unroll
        for (int nf = 0; nf < 4; nf++) {
          const float v = acc[mf][nf][r] + bb[nf];
          sj[nf] += v;
          out[(size_t)(m0 + rowL) * DIM + n0 + wn * 64 + nf * 16 + l15] = (bf16_t)v;
        }
      }
    // sent(h): block rows are batch-uniform (m0 % 256 == 0, SEQ % 256 == 0)
#pragma unroll
    for (int nf = 0; nf < 4; nf++) {
      sj[nf] += __shfl_xor(sj[nf], 16);
      sj[nf] += __shfl_xor(sj[nf], 32);
    }
    if (quad == 0)
#pragma unroll
      for (int nf = 0; nf < 4; nf++)
        atomicAdd(&sent[(m0 >> 11) * DIM + n0 + wn * 64 + nf * 16 + l15],
                  sj[nf] * (1.0f / SEQ));
  } else if constexpr (MODE == 1) {
#pragma unroll
    for (int mf = 0; mf < 8; mf++)
#pragma unroll
      for (int r = 0; r < 4; r++) {
        const int c = m0 + wm * 128 + mf * 16 + quad * 4 + r;
        if (c < count) {
          const int tkn = tk[c];
          const float g = gate[tkn];
#pragma unroll
          for (int nf = 0; nf < 4; nf++)
            out[(size_t)tkn * DIM + n0 + wn * 64 + nf * 16 + l15] =
                (bf16_t)((acc[mf][nf][r] + bb[nf]) * g);
        }
      }
  } else {
    // MODE 2: zero-atomic fused column-sum (r18 lesson: LDS f32 atomicAdd
    // = CAS loop). Register buckets (static idx), shfl quad-fold, per-wm
    // LDS slices overlaid on dead As, single 8 KB slab store.
    float colacc[4][8];  // [nf][b] -- fully unrolled, static indexing
#pragma unroll
    for (int nf = 0; nf < 4; nf++)
#pragma unroll
      for (int b2 = 0; b2 < 8; b2++) colacc[nf][b2] = 0.f;
#pragma unroll
    for (int mf = 0; mf < 8; mf++)
#pragma unroll
      for (int r = 0; r < 4; r++) {
        const int c = m0 + wm * 128 + mf * 16 + quad * 4 + r;
        if (c < count) {
          const int tkn = tk[c];
          const float g = gate[tkn];
          const int b = tkn >> 11;  // SEQ = 2048
#pragma unroll
          for (int nf = 0; nf < 4; nf++) {
            const float v = (acc[mf][nf][r] + bb[nf]) * g;
#pragma unroll
            for (int b2 = 0; b2 < 8; b2++)
              colacc[nf][b2] += (b == b2) ? v : 0.f;
          }
        }
      }
    // fold quads: col = wn*64 + nf*16 + l15 is quad-invariant
#pragma unroll
    for (int nf = 0; nf < 4; nf++)
#pragma unroll
      for (int b2 = 0; b2 < 8; b2++) {
        colacc[nf][b2] += __shfl_xor(colacc[nf][b2], 16);
        colacc[nf][b2] += __shfl_xor(colacc[nf][b2], 32);
      }
    __syncthreads();  // all LDS reads (MFMA operands) complete -> reuse As
    float* swm = (float*)&As[0][0];  // [2][8][256] = 16 KB, per-wm slices
    if (quad == 0) {
#pragma unroll
      for (int nf = 0; nf < 4; nf++)
#pragma unroll
        for (int b2 = 0; b2 < 8; b2++)
          swm[(wm * 8 + b2) * 256 + wn * 64 + nf * 16 + l15] = colacc[nf][b2];
    }
    __syncthreads();
    float* slab = slabs + (size_t)id * 2048;
    for (int i = tid; i < 2048; i += 512)
      slab[i] = swm[i] + swm[2048 + i];
  }
}

// ---------------- MFMA gating (r5-verified) --------------------------------
__global__ __launch_bounds__(256) void k_gate_mm(
    const bf16_t* __restrict__ act, const bf16_t* __restrict__ WgPx,
    int* __restrict__ idx, float* __restrict__ gate) {
  __shared__ alignas(16) bf16_t As[64 * 64];    // 8 KB
  __shared__ alignas(16) bf16_t WgS[128 * 64];  // 16 KB
  __shared__ float L[64][8];
  const int tid = threadIdx.x;
  const int lane = tid & 63, wave = tid >> 6;
  const int quad = lane >> 4, l15 = lane & 15;
  const int m0 = blockIdx.x * 64;
  const int kc = (tid & 7) ^ ((tid >> 3) & 7);
  const int rbase = tid >> 3;

#pragma unroll
  for (int j = 0; j < 4; j++)
    gll16(WgPx + (j * 256 + wave * 64 + lane) * 8, &WgS[(j * 256 + wave * 64) * 8]);

  const bf16_t* gA[2]; bf16_t* lA[2];
#pragma unroll
  for (int i = 0; i < 2; i++) {
    gA[i] = act + (size_t)(m0 + rbase + 32 * i) * DIM + kc * 8;
    lA[i] = &As[wave * 512 + i * 2048];
  }
  fx4 acc = (fx4)0.0f;
  for (int k0 = 0; k0 < DIM; k0 += 64) {
#pragma unroll
    for (int i = 0; i < 2; i++) gll16(gA[i] + k0, lA[i]);
    __syncthreads();
#pragma unroll
    for (int s = 0; s < 2; s++) {
      const int pofs = ((s * 4 + quad) ^ (l15 & 7)) << 3;
      bf16x8 av = *(const bf16x8*)&As[(wave * 16 + l15) * 64 + pofs];
      bf16x8 bv = *(const bf16x8*)&WgS[((k0 >> 3) + s * 4 + quad) * 64 + (l15 & 7) * 8];
      acc = __builtin_amdgcn_mfma_f32_16x16x32_bf16(av, bv, acc, 0, 0, 0);
    }
    __syncthreads();
  }
  if (l15 < 8) {
#pragma unroll
    for (int r = 0; r < 4; r++) L[wave * 16 + quad * 4 + r][l15] = acc[r];
  }
  __syncthreads();
  if (tid < 64) {
    float lg[8];
#pragma unroll
    for (int e = 0; e < 8; e++) lg[e] = L[tid][e];
    float best = lg[0];
    int bi = 0;
#pragma unroll
    for (int e = 1; e < 8; e++)
      if (lg[e] > best) { best = lg[e]; bi = e; }  // strict >: first max wins
    float s = 0.f;
#pragma unroll
    for (int e = 0; e < 8; e++) s += expf(lg[e] - best);
    idx[m0 + tid] = bi;
    gate[m0 + tid] = 1.0f / s;
  }
}

// ---------------- route: tok list + capacity drop + zero dropped rows ------
#define DLMAX 2048
__global__ __launch_bounds__(1024) void k_route(
    const int* __restrict__ idx, int* __restrict__ tok, int* __restrict__ cnt,
    bf16_t* __restrict__ obuf) {
  const int e = blockIdx.x;
  const int tid = threadIdx.x, lane = tid & 63, wv = tid >> 6;
  __shared__ int wsum[16];
  __shared__ int dlist[DLMAX];
  const int4* p = (const int4*)(idx + tid * 16);
  int m[16];
  int c = 0;
#pragma unroll
  for (int j = 0; j < 4; j++) {
    int4 v = p[j];
    m[j * 4 + 0] = (v.x == e);
    m[j * 4 + 1] = (v.y == e);
    m[j * 4 + 2] = (v.z == e);
    m[j * 4 + 3] = (v.w == e);
    c += m[j * 4] + m[j * 4 + 1] + m[j * 4 + 2] + m[j * 4 + 3];
  }
  int sc = c;  // intra-wave inclusive scan
#pragma unroll
  for (int off = 1; off < 64; off <<= 1) {
    int n = __shfl_up(sc, off);
    if (lane >= off) sc += n;
  }
  if (lane == 63) wsum[wv] = sc;
  __syncthreads();
  int wb = 0, tot = 0;
#pragma unroll
  for (int i = 0; i < 16; i++) {
    int s = wsum[i];
    tot += s;
    if (i < wv) wb += s;
  }
  int pos = wb + sc - c;  // exclusive prefix
  const uint4 z = {0u, 0u, 0u, 0u};
#pragma unroll
  for (int j = 0; j < 16; j++) {
    if (m[j]) {
      int t = tid * 16 + j;
      if (pos < CAP) {
        tok[e * CAP + pos] = t;
      } else {
        int di = pos - CAP;
        if (di < DLMAX) dlist[di] = t;
        else  // pathological overflow: zero directly
          for (int k = 0; k < 128; k++) *(uint4*)&obuf[(size_t)t * DIM + k * 8] = z;
      }
      pos++;
    }
  }
  if (tid == 0) cnt[e] = tot < CAP ? tot : CAP;
  __syncthreads();
  int ndl = tot - CAP;
  ndl = ndl < 0 ? 0 : (ndl > DLMAX ? DLMAX : ndl);
  for (int d = tid >> 7; d < ndl; d += 8) {  // 128 thr/row, 8 rows at a time
    int t = dlist[d];
    *(uint4*)&obuf[(size_t)t * DIM + (tid & 127) * 8] = z;
  }
}

// ---------------- k_sum: slabs + sent(h) -> sentF (no atomics) -------------
// grid 32: b = bid>>2, sub(ntile) = bid&3. slab id = rem*8+xcd, ntile=rem&3.
__global__ __launch_bounds__(256) void k_sum(
    const float* __restrict__ slabs, const float* __restrict__ sent,
    float* __restrict__ sentF) {
  const int b = blockIdx.x >> 2, sub = blockIdx.x & 3;
  const int tid = threadIdx.x;
  float a = 0.f;
#pragma unroll 1
  for (int rg = 0; rg < 8; rg++) {
    const int rem = rg * 4 + sub;
#pragma unroll
    for (int xcd = 0; xcd < 8; xcd++)
      a += slabs[(size_t)(rem * 8 + xcd) * 2048 + b * 256 + tid];
  }
  const int col = sub * 256 + tid;
  sentF[b * DIM + col] = sent[b * DIM + col] + a * (1.0f / SEQ);
}

// ---------------- k_loss: CE from sentF (1 block) --------------------------
__global__ __launch_bounds__(256) void k_loss(
    const float* __restrict__ sentF, const int* __restrict__ y,
    float* __restrict__ out) {
  const int tid = threadIdx.x;
  __shared__ float red[256];
  float total = 0.f;
  for (int b = 0; b < BATCH; b++) {
    const int c4 = tid * 4;
    float4 f = *(const float4*)&sentF[b * DIM + c4];
    float m = fmaxf(fmaxf(f.x, f.y), fmaxf(f.z, f.w));
    red[tid] = m;
    __syncthreads();
    for (int s = 128; s; s >>= 1) {
      if (tid < s) red[tid] = fmaxf(red[tid], red[tid + s]);
      __syncthreads();
    }
    m = red[0];
    __syncthreads();
    float sum = expf(f.x - m) + expf(f.y - m) + expf(f.z - m) + expf(f.w - m);
    red[tid] = sum;
    __syncthreads();
    for (int s = 128; s; s >>= 1) {
      if (tid < s) red[tid] += red[tid + s];
      __syncthreads();
    }
    if (tid == 0) total += m + logf(red[0]) - sentF[b * DIM + y[b]];
    __syncthreads();
  }
  if (tid == 0) out[0] = total * (1.0f / BATCH);
}

// ---------------------------------------------------------------------------
extern "C" void kernel_launch(void* const* d_in, const int* in_sizes, int n_in,
                              void* d_out, int out_size, void* d_ws, size_t ws_size,
                              hipStream_t stream) {
  (void)in_sizes; (void)n_in; (void)out_size; (void)ws_size;
  const float* x   = (const float*)d_in[0];
  const int*   y   = (const int*)d_in[1];
  const float* W1  = (const float*)d_in[2];
  const float* b1  = (const float*)d_in[3];
  const float* Wg2 = (const float*)d_in[4];
  const float* We2 = (const float*)d_in[5];
  const float* be2 = (const float*)d_in[6];
  const float* Wg3 = (const float*)d_in[7];
  const float* We3 = (const float*)d_in[8];
  const float* be3 = (const float*)d_in[9];

  char* p = (char*)d_ws;
  size_t off = 0;
  auto carve = [&](size_t bytes) -> char* {
    char* r = p + off;
    off += (bytes + 255) & ~(size_t)255;
    return r;
  };
  bf16_t* Wt   = (bf16_t*)carve((size_t)17 * DIM * DIM * 2);  // 0:W1t 1..8:We2t 9..16:We3t
  bf16_t* WgP  = (bf16_t*)carve(2 * 128 * 8 * 8 * 2);         // gate B-frag packs
  bf16_t* h    = (bf16_t*)carve((size_t)TOKS * DIM * 2);
  bf16_t* o1   = (bf16_t*)carve((size_t)TOKS * DIM * 2);
  bf16_t* o2   = (bf16_t*)carve((size_t)TOKS * DIM * 2);  // aliases xb lifetime
  int*    idx  = (int*)carve(TOKS * 4);
  float*  gate = (float*)carve(TOKS * 4);
  int*    tok  = (int*)carve(NEXP * CAP * 4);
  int*    cnt  = (int*)carve(NEXP * 4);
  // --- contiguous zero region (filled by prep_x's last block) ---
  size_t zoff0 = off;
  float*  sent = (float*)carve(BATCH * DIM * 4);
  bf16_t* zp   = (bf16_t*)carve(4096);
  size_t zbytes = off - zoff0;
  // --- outside zero region: fully written before read, no zeroing needed ---
  float*  slabs = (float*)carve((size_t)256 * 2048 * 4);  // 2 MB MODE2 slabs
  float*  sentF = (float*)carve((size_t)BATCH * DIM * 4);
  bf16_t* xb   = o2;  // x-bf16 dead before o2 is born (route3)

  // prep: weight transpose+cvt | Wg pack + x cvt + zero-fill
  k_prep_w<<<PW_BLOCKS, 256, 0, stream>>>(W1, We2, We3, Wt);
  k_prep_x<<<PREPX_GRID, 256, 0, stream>>>(
      Wg2, Wg3, x, WgP, xb, (uint4*)sent, (int)(zbytes / 16));

  // dense pre-layer (+ fused sent(h)): 64 x 4 tiles of 256^2 = 256 blocks
  k_gemm256<0><<<256, 512, 0, stream>>>(
      xb, Wt, b1, h, sent, nullptr, nullptr, nullptr, zp, nullptr);

  // MoE layer 2
  k_gate_mm<<<TOKS / 64, 256, 0, stream>>>(h, WgP, idx, gate);
  k_route<<<NEXP, 1024, 0, stream>>>(idx, tok, cnt, o1);
  k_gemm256<1><<<256, 512, 0, stream>>>(
      h, Wt + (size_t)1 * DIM * DIM, be2, o1, nullptr, tok, cnt, gate, zp, nullptr);

  // MoE layer 3 (expert output never materialized: fused column-sum)
  k_gate_mm<<<TOKS / 64, 256, 0, stream>>>(o1, WgP + 128 * 8 * 8, idx, gate);
  k_route<<<NEXP, 1024, 0, stream>>>(idx, tok, cnt, o2);
  k_gemm256<2><<<256, 512, 0, stream>>>(
      o1, Wt + (size_t)9 * DIM * DIM, be3, nullptr, nullptr, tok, cnt, gate, zp, slabs);

  // slabs + sent -> sentF -> CE loss (kernel-boundary sync, no counters)
  k_sum<<<32, 256, 0, stream>>>(slabs, sent, sentF);
  k_loss<<<1, 256, 0, stream>>>(sentF, y, (float*)d_out);
}